// Round 4
// baseline (1079.601 us; speedup 1.0000x reference)
//
#include <hip/hip_runtime.h>

#define NN 16384
#define DIM 64
#define RSBLK 2048              // rowsum blocks: 8 per CU, all co-resident
#define ROWS_PER_BLK 8          // NN / RSBLK
#define UPDBLK 256              // update blocks: 1 per CU
#define RPB_U (NN / UPDBLK)     // 64 rows per update block
#define SLOT (RSBLK * DIM)      // floats per partials slot

// ---- fused: rowwise relu-sums of graph + u1 = relu(base) + partials slot 0 ----
__global__ __launch_bounds__(256, 8) void rowsum_init_kernel(
    const float* __restrict__ g, const int* __restrict__ s_mask,
    const float* __restrict__ W3, const float* __restrict__ w4,
    const float* __restrict__ w1,
    float* __restrict__ pos, float* __restrict__ neg,
    float* __restrict__ u, float* __restrict__ partials)
{
    __shared__ float a3s[DIM], b3s[DIM], w1s[DIM];
    __shared__ float ps[4][DIM];
    const int tid  = threadIdx.x;
    const int wid  = tid >> 6;
    const int lane = tid & 63;
    const int row0 = blockIdx.x * ROWS_PER_BLK;

    if (tid < DIM) {
        float a = 0.f, bb = 0.f;
        for (int k = 0; k < DIM; ++k) {
            const float w = W3[tid * DIM + k];
            a  += w * fmaxf(w4[k], 0.f);
            bb += w * fmaxf(-w4[k], 0.f);
        }
        a3s[tid] = a; b3s[tid] = bb; w1s[tid] = w1[tid];
    }
    __syncthreads();

    float uacc = 0.f;
    #pragma unroll
    for (int rr = 0; rr < 2; ++rr) {
        const int row = row0 + wid * 2 + rr;
        const float4* grow = reinterpret_cast<const float4*>(g + (size_t)row * NN);
        float p = 0.f, n = 0.f;
        #pragma unroll 4
        for (int i = lane; i < NN / 4; i += 64) {
            const float4 v = grow[i];
            p += fmaxf(v.x, 0.f) + fmaxf(v.y, 0.f) + fmaxf(v.z, 0.f) + fmaxf(v.w, 0.f);
            n += fmaxf(-v.x, 0.f) + fmaxf(-v.y, 0.f) + fmaxf(-v.z, 0.f) + fmaxf(-v.w, 0.f);
        }
        #pragma unroll
        for (int o = 1; o < 64; o <<= 1) {
            p += __shfl_xor(p, o, 64);
            n += __shfl_xor(n, o, 64);
        }
        const float x  = (float)s_mask[row];
        const float uu = fmaxf(x * w1s[lane] + p * a3s[lane] + n * b3s[lane], 0.f);
        u[(size_t)row * DIM + lane] = uu;
        uacc += uu;
        if (lane == 0) { pos[row] = p; neg[row] = n; }
    }
    ps[wid][lane] = uacc;
    __syncthreads();
    if (tid < DIM)
        partials[blockIdx.x * DIM + tid] = ps[0][tid] + ps[1][tid] + ps[2][tid] + ps[3][tid];
}

// ---- one message-passing iteration ----
__global__ __launch_bounds__(256) void upd_kernel(
    const int* __restrict__ s_mask, const float* __restrict__ w1,
    const float* __restrict__ W2, const float* __restrict__ W3,
    const float* __restrict__ w4,
    const float* __restrict__ pos, const float* __restrict__ neg,
    float* __restrict__ u, float* __restrict__ partials,
    int slot_in, int Pcount)
{
    __shared__ float a3s[DIM], b3s[DIM], w1s[DIM], ss[DIM];
    __shared__ float posr[RPB_U], negr[RPB_U], xr[RPB_U];
    __shared__ float4 ps4[16][16];
    __shared__ float ps[4][DIM];
    const int tid  = threadIdx.x;
    const int row0 = blockIdx.x * RPB_U;

    if (tid < 64) {
        float a = 0.f, bb = 0.f;
        for (int k = 0; k < DIM; ++k) {
            const float w = W3[tid * DIM + k];
            a  += w * fmaxf(w4[k], 0.f);
            bb += w * fmaxf(-w4[k], 0.f);
        }
        a3s[tid] = a; b3s[tid] = bb; w1s[tid] = w1[tid];
    } else if (tid < 128) {
        posr[tid - 64] = pos[row0 + tid - 64];
    } else if (tid < 192) {
        negr[tid - 128] = neg[row0 + tid - 128];
    } else {
        xr[tid - 192] = (float)s_mask[row0 + tid - 192];
    }

    {
        const int d4 = tid & 15, s16 = tid >> 4;
        const float4* pin = reinterpret_cast<const float4*>(partials + (size_t)slot_in * SLOT);
        float4 a4 = {0.f, 0.f, 0.f, 0.f};
        for (int p = s16; p < Pcount; p += 16) {
            const float4 t4 = pin[p * 16 + d4];
            a4.x += t4.x; a4.y += t4.y; a4.z += t4.z; a4.w += t4.w;
        }
        ps4[s16][d4] = a4;
        __syncthreads();
        if (tid < 16) {
            float4 r = ps4[0][tid];
            #pragma unroll
            for (int s = 1; s < 16; ++s) {
                const float4 t4 = ps4[s][tid];
                r.x += t4.x; r.y += t4.y; r.z += t4.z; r.w += t4.w;
            }
            reinterpret_cast<float4*>(ss)[tid] = r;
        }
        __syncthreads();
    }

    const int d = tid & 63, sub = tid >> 6;
    float w2r[DIM];
    #pragma unroll
    for (int k = 0; k < DIM; k += 4) {
        const float4 t = *reinterpret_cast<const float4*>(&W2[d * DIM + k]);
        w2r[k] = t.x; w2r[k + 1] = t.y; w2r[k + 2] = t.z; w2r[k + 3] = t.w;
    }
    float c2 = 0.f;
    #pragma unroll
    for (int k = 0; k < DIM; ++k) c2 += w2r[k] * ss[k];

    float uacc = 0.f;
    for (int r = sub; r < RPB_U; r += 4) {
        const int row = row0 + r;
        const float4* ur = reinterpret_cast<const float4*>(u + (size_t)row * DIM);
        float aA = 0.f, aB = 0.f, aC = 0.f, aD = 0.f;
        #pragma unroll
        for (int k4 = 0; k4 < 16; k4 += 4) {
            const float4 x0 = ur[k4 + 0];
            aA += w2r[(k4+0)*4+0]*x0.x + w2r[(k4+0)*4+1]*x0.y + w2r[(k4+0)*4+2]*x0.z + w2r[(k4+0)*4+3]*x0.w;
            const float4 x1 = ur[k4 + 1];
            aB += w2r[(k4+1)*4+0]*x1.x + w2r[(k4+1)*4+1]*x1.y + w2r[(k4+1)*4+2]*x1.z + w2r[(k4+1)*4+3]*x1.w;
            const float4 x2 = ur[k4 + 2];
            aC += w2r[(k4+2)*4+0]*x2.x + w2r[(k4+2)*4+1]*x2.y + w2r[(k4+2)*4+2]*x2.z + w2r[(k4+2)*4+3]*x2.w;
            const float4 x3 = ur[k4 + 3];
            aD += w2r[(k4+3)*4+0]*x3.x + w2r[(k4+3)*4+1]*x3.y + w2r[(k4+3)*4+2]*x3.z + w2r[(k4+3)*4+3]*x3.w;
        }
        const float acc = (aA + aB) + (aC + aD);
        const float uu = fmaxf(xr[r] * w1s[d] + posr[r] * a3s[d] + negr[r] * b3s[d] + c2 - acc, 0.f);
        u[(size_t)row * DIM + d] = uu;
        uacc += uu;
    }
    ps[sub][d] = uacc;
    __syncthreads();
    if (tid < DIM)
        partials[(size_t)(slot_in + 1) * SLOT + blockIdx.x * DIM + tid] =
            ps[0][tid] + ps[1][tid] + ps[2][tid] + ps[3][tid];
}

// ---- q(v) head ----
__global__ void final_kernel(const float* __restrict__ partials_slot,
                             const float* __restrict__ u, const int* __restrict__ vptr,
                             const float* __restrict__ W6, const float* __restrict__ W7,
                             const float* __restrict__ w5, float* __restrict__ out)
{
    __shared__ float ps[2][DIM], ss[DIM], hred[128];
    const int tid = threadIdx.x;
    const int d = tid & 63, sub = tid >> 6;
    float acc = 0.f;
    for (int p = sub; p < UPDBLK; p += 2) acc += partials_slot[p * DIM + d];
    ps[sub][d] = acc;
    __syncthreads();
    if (tid < 64) ss[tid] = ps[0][tid] + ps[1][tid];
    __syncthreads();
    const int v = *vptr;
    float h = 0.f;
    if (tid < 64) {
        #pragma unroll
        for (int k = 0; k < DIM; ++k) h += W6[tid * DIM + k] * ss[k];
    } else {
        const float* uv = u + (size_t)v * DIM;
        #pragma unroll
        for (int k = 0; k < DIM; ++k) h += W7[(tid - 64) * DIM + k] * uv[k];
    }
    hred[tid] = fmaxf(h, 0.f) * w5[tid];
    __syncthreads();
    if (tid == 0) {
        float s = 0.f;
        for (int i = 0; i < 128; ++i) s += hred[i];
        out[0] = s;
    }
}

// ---- DIAGNOSTIC: pure-read BW probe. Reads the whole graph 4x (pass-shifted
// by 512 MB so neither L2 nor L3 can serve it) and writes 1 float/block.
// Guaranteed >650 us so it lands in rocprof top-5 with its own hbm_gbps. ----
__global__ __launch_bounds__(256, 8) void bw_probe_kernel(
    const float* __restrict__ g, float* __restrict__ scrap)
{
    const int tid  = threadIdx.x;
    const int wid  = tid >> 6;
    const int lane = tid & 63;
    float acc = 0.f;
    #pragma unroll
    for (int pass = 0; pass < 4; ++pass) {
        const int blk  = (blockIdx.x + pass * 1024) & (RSBLK - 1);
        const int row0 = blk * ROWS_PER_BLK;
        for (int rr = 0; rr < 2; ++rr) {
            const int row = row0 + wid * 2 + rr;
            const float4* grow = reinterpret_cast<const float4*>(g + (size_t)row * NN);
            #pragma unroll 4
            for (int i = lane; i < NN / 4; i += 64) {
                const float4 v = grow[i];
                acc += v.x + v.y + v.z + v.w;
            }
        }
    }
    __shared__ float red[256];
    red[tid] = acc;
    __syncthreads();
    if (tid == 0) {
        float s = 0.f;
        for (int i = 0; i < 256; ++i) s += red[i];
        scrap[blockIdx.x] = s;
    }
}

extern "C" void kernel_launch(void* const* d_in, const int* in_sizes, int n_in,
                              void* d_out, int out_size, void* d_ws, size_t ws_size,
                              hipStream_t stream) {
    const float* graph  = (const float*)d_in[0];
    const int*   s_mask = (const int*)d_in[1];
    const int*   vptr   = (const int*)d_in[2];
    const float* w1     = (const float*)d_in[3];
    const float* W2     = (const float*)d_in[4];
    const float* W3     = (const float*)d_in[5];
    const float* w4     = (const float*)d_in[6];
    const float* w5     = (const float*)d_in[7];
    const float* W6     = (const float*)d_in[8];
    const float* W7     = (const float*)d_in[9];
    float* out = (float*)d_out;

    float* ws       = (float*)d_ws;
    float* pos      = ws;                          // NN
    float* neg      = pos + NN;                    // NN
    float* u        = neg + NN;                    // NN*DIM
    float* partials = u + (size_t)NN * DIM;        // 4 * SLOT
    float* scrap    = partials + (size_t)4 * SLOT; // RSBLK

    rowsum_init_kernel<<<RSBLK, 256, 0, stream>>>(graph, s_mask, W3, w4, w1,
                                                  pos, neg, u, partials);
    upd_kernel<<<UPDBLK, 256, 0, stream>>>(s_mask, w1, W2, W3, w4, pos, neg,
                                           u, partials, 0, RSBLK);
    upd_kernel<<<UPDBLK, 256, 0, stream>>>(s_mask, w1, W2, W3, w4, pos, neg,
                                           u, partials, 1, UPDBLK);
    upd_kernel<<<UPDBLK, 256, 0, stream>>>(s_mask, w1, W2, W3, w4, pos, neg,
                                           u, partials, 2, UPDBLK);
    final_kernel<<<1, 128, 0, stream>>>(partials + (size_t)3 * SLOT, u, vptr,
                                        W6, W7, w5, out);
    // diagnostic only — remove next round
    bw_probe_kernel<<<RSBLK, 256, 0, stream>>>(graph, scrap);
}

// Round 6
// 381.985 us; speedup vs baseline: 2.8263x; 2.8263x over previous
//
#include <hip/hip_runtime.h>

#define NN 16384
#define DIM 64
#define RSBLK 2048              // rowsum blocks: 8 per CU, all co-resident
#define ROWS_PER_BLK 8          // NN / RSBLK
#define UPDBLK 256              // update blocks: 1 per CU
#define RPB_U (NN / UPDBLK)     // 64 rows per update block
#define SLOT (RSBLK * DIM)      // floats per partials slot

typedef float floatx4 __attribute__((ext_vector_type(4)));  // native vec for nt loads

// ---- fused: rowwise relu-sums of graph + u1 = relu(base) + partials slot 0 ----
// One wave per row; nt loads (no L2/L3 allocate) + explicit 8-deep batch.
// Uses sum/abs identity: relu(x)+relu(-x)=|x|, relu(x)-relu(-x)=x.
__global__ __launch_bounds__(256, 8) void rowsum_init_kernel(
    const float* __restrict__ g, const int* __restrict__ s_mask,
    const float* __restrict__ W3, const float* __restrict__ w4,
    const float* __restrict__ w1,
    float* __restrict__ pos, float* __restrict__ neg,
    float* __restrict__ u, float* __restrict__ partials)
{
    __shared__ float a3s[DIM], b3s[DIM], w1s[DIM];
    __shared__ float ps[4][DIM];
    const int tid  = threadIdx.x;
    const int wid  = tid >> 6;
    const int lane = tid & 63;
    const int row0 = blockIdx.x * ROWS_PER_BLK;

    if (tid < DIM) {  // a3 = W3@relu(w4), b3 = W3@relu(-w4) (redundant per block)
        float a = 0.f, bb = 0.f;
        for (int k = 0; k < DIM; ++k) {
            const float w = W3[tid * DIM + k];
            a  += w * fmaxf(w4[k], 0.f);
            bb += w * fmaxf(-w4[k], 0.f);
        }
        a3s[tid] = a; b3s[tid] = bb; w1s[tid] = w1[tid];
    }
    __syncthreads();

    float uacc = 0.f;
    #pragma unroll
    for (int rr = 0; rr < 2; ++rr) {
        const int row = row0 + wid * 2 + rr;
        const floatx4* grow = reinterpret_cast<const floatx4*>(g + (size_t)row * NN);
        float s = 0.f, a = 0.f;   // s = sum(x), a = sum(|x|)
        for (int b8 = 0; b8 < 8; ++b8) {   // 64 float4/lane = 8 batches of 8
            floatx4 v[8];
            #pragma unroll
            for (int j = 0; j < 8; ++j)
                v[j] = __builtin_nontemporal_load(&grow[(b8 * 8 + j) * 64 + lane]);
            #pragma unroll
            for (int j = 0; j < 8; ++j) {
                s += v[j].x + v[j].y + v[j].z + v[j].w;
                a += fabsf(v[j].x) + fabsf(v[j].y) + fabsf(v[j].z) + fabsf(v[j].w);
            }
        }
        float p = 0.5f * (a + s);   // = sum(relu(x))
        float n = 0.5f * (a - s);   // = sum(relu(-x))
        #pragma unroll
        for (int o = 1; o < 64; o <<= 1) {  // butterfly: all lanes get the row sums
            p += __shfl_xor(p, o, 64);
            n += __shfl_xor(n, o, 64);
        }
        const float x  = (float)s_mask[row];
        const float uu = fmaxf(x * w1s[lane] + p * a3s[lane] + n * b3s[lane], 0.f);
        u[(size_t)row * DIM + lane] = uu;
        uacc += uu;
        if (lane == 0) { pos[row] = p; neg[row] = n; }
    }
    ps[wid][lane] = uacc;
    __syncthreads();
    if (tid < DIM)
        partials[blockIdx.x * DIM + tid] = ps[0][tid] + ps[1][tid] + ps[2][tid] + ps[3][tid];
}

// ---- one message-passing iteration ----
__global__ __launch_bounds__(256) void upd_kernel(
    const int* __restrict__ s_mask, const float* __restrict__ w1,
    const float* __restrict__ W2, const float* __restrict__ W3,
    const float* __restrict__ w4,
    const float* __restrict__ pos, const float* __restrict__ neg,
    float* __restrict__ u, float* __restrict__ partials,
    int slot_in, int Pcount)
{
    __shared__ float a3s[DIM], b3s[DIM], w1s[DIM], ss[DIM];
    __shared__ float posr[RPB_U], negr[RPB_U], xr[RPB_U];
    __shared__ float4 ps4[16][16];
    __shared__ float ps[4][DIM];
    const int tid  = threadIdx.x;
    const int row0 = blockIdx.x * RPB_U;

    if (tid < 64) {
        float a = 0.f, bb = 0.f;
        for (int k = 0; k < DIM; ++k) {
            const float w = W3[tid * DIM + k];
            a  += w * fmaxf(w4[k], 0.f);
            bb += w * fmaxf(-w4[k], 0.f);
        }
        a3s[tid] = a; b3s[tid] = bb; w1s[tid] = w1[tid];
    } else if (tid < 128) {
        posr[tid - 64] = pos[row0 + tid - 64];
    } else if (tid < 192) {
        negr[tid - 128] = neg[row0 + tid - 128];
    } else {
        xr[tid - 192] = (float)s_mask[row0 + tid - 192];
    }

    {
        const int d4 = tid & 15, s16 = tid >> 4;
        const float4* pin = reinterpret_cast<const float4*>(partials + (size_t)slot_in * SLOT);
        float4 a4 = {0.f, 0.f, 0.f, 0.f};
        for (int p = s16; p < Pcount; p += 16) {
            const float4 t4 = pin[p * 16 + d4];
            a4.x += t4.x; a4.y += t4.y; a4.z += t4.z; a4.w += t4.w;
        }
        ps4[s16][d4] = a4;
        __syncthreads();
        if (tid < 16) {
            float4 r = ps4[0][tid];
            #pragma unroll
            for (int s = 1; s < 16; ++s) {
                const float4 t4 = ps4[s][tid];
                r.x += t4.x; r.y += t4.y; r.z += t4.z; r.w += t4.w;
            }
            reinterpret_cast<float4*>(ss)[tid] = r;
        }
        __syncthreads();
    }

    const int d = tid & 63, sub = tid >> 6;
    float w2r[DIM];
    #pragma unroll
    for (int k = 0; k < DIM; k += 4) {
        const float4 t = *reinterpret_cast<const float4*>(&W2[d * DIM + k]);
        w2r[k] = t.x; w2r[k + 1] = t.y; w2r[k + 2] = t.z; w2r[k + 3] = t.w;
    }
    float c2 = 0.f;
    #pragma unroll
    for (int k = 0; k < DIM; ++k) c2 += w2r[k] * ss[k];

    float uacc = 0.f;
    for (int r = sub; r < RPB_U; r += 4) {
        const int row = row0 + r;
        const float4* ur = reinterpret_cast<const float4*>(u + (size_t)row * DIM);
        float aA = 0.f, aB = 0.f, aC = 0.f, aD = 0.f;
        #pragma unroll
        for (int k4 = 0; k4 < 16; k4 += 4) {
            const float4 x0 = ur[k4 + 0];
            aA += w2r[(k4+0)*4+0]*x0.x + w2r[(k4+0)*4+1]*x0.y + w2r[(k4+0)*4+2]*x0.z + w2r[(k4+0)*4+3]*x0.w;
            const float4 x1 = ur[k4 + 1];
            aB += w2r[(k4+1)*4+0]*x1.x + w2r[(k4+1)*4+1]*x1.y + w2r[(k4+1)*4+2]*x1.z + w2r[(k4+1)*4+3]*x1.w;
            const float4 x2 = ur[k4 + 2];
            aC += w2r[(k4+2)*4+0]*x2.x + w2r[(k4+2)*4+1]*x2.y + w2r[(k4+2)*4+2]*x2.z + w2r[(k4+2)*4+3]*x2.w;
            const float4 x3 = ur[k4 + 3];
            aD += w2r[(k4+3)*4+0]*x3.x + w2r[(k4+3)*4+1]*x3.y + w2r[(k4+3)*4+2]*x3.z + w2r[(k4+3)*4+3]*x3.w;
        }
        const float acc = (aA + aB) + (aC + aD);
        const float uu = fmaxf(xr[r] * w1s[d] + posr[r] * a3s[d] + negr[r] * b3s[d] + c2 - acc, 0.f);
        u[(size_t)row * DIM + d] = uu;
        uacc += uu;
    }
    ps[sub][d] = uacc;
    __syncthreads();
    if (tid < DIM)
        partials[(size_t)(slot_in + 1) * SLOT + blockIdx.x * DIM + tid] =
            ps[0][tid] + ps[1][tid] + ps[2][tid] + ps[3][tid];
}

// ---- q(v) head ----
__global__ void final_kernel(const float* __restrict__ partials_slot,
                             const float* __restrict__ u, const int* __restrict__ vptr,
                             const float* __restrict__ W6, const float* __restrict__ W7,
                             const float* __restrict__ w5, float* __restrict__ out)
{
    __shared__ float ps[2][DIM], ss[DIM], hred[128];
    const int tid = threadIdx.x;
    const int d = tid & 63, sub = tid >> 6;
    float acc = 0.f;
    for (int p = sub; p < UPDBLK; p += 2) acc += partials_slot[p * DIM + d];
    ps[sub][d] = acc;
    __syncthreads();
    if (tid < 64) ss[tid] = ps[0][tid] + ps[1][tid];
    __syncthreads();
    const int v = *vptr;
    float h = 0.f;
    if (tid < 64) {
        #pragma unroll
        for (int k = 0; k < DIM; ++k) h += W6[tid * DIM + k] * ss[k];
    } else {
        const float* uv = u + (size_t)v * DIM;
        #pragma unroll
        for (int k = 0; k < DIM; ++k) h += W7[(tid - 64) * DIM + k] * uv[k];
    }
    hred[tid] = fmaxf(h, 0.f) * w5[tid];
    __syncthreads();
    if (tid == 0) {
        float s = 0.f;
        for (int i = 0; i < 128; ++i) s += hred[i];
        out[0] = s;
    }
}

extern "C" void kernel_launch(void* const* d_in, const int* in_sizes, int n_in,
                              void* d_out, int out_size, void* d_ws, size_t ws_size,
                              hipStream_t stream) {
    const float* graph  = (const float*)d_in[0];
    const int*   s_mask = (const int*)d_in[1];
    const int*   vptr   = (const int*)d_in[2];
    const float* w1     = (const float*)d_in[3];
    const float* W2     = (const float*)d_in[4];
    const float* W3     = (const float*)d_in[5];
    const float* w4     = (const float*)d_in[6];
    const float* w5     = (const float*)d_in[7];
    const float* W6     = (const float*)d_in[8];
    const float* W7     = (const float*)d_in[9];
    float* out = (float*)d_out;

    float* ws       = (float*)d_ws;
    float* pos      = ws;                      // NN
    float* neg      = pos + NN;                // NN
    float* u        = neg + NN;                // NN*DIM
    float* partials = u + (size_t)NN * DIM;    // 4 * SLOT

    rowsum_init_kernel<<<RSBLK, 256, 0, stream>>>(graph, s_mask, W3, w4, w1,
                                                  pos, neg, u, partials);
    upd_kernel<<<UPDBLK, 256, 0, stream>>>(s_mask, w1, W2, W3, w4, pos, neg,
                                           u, partials, 0, RSBLK);
    upd_kernel<<<UPDBLK, 256, 0, stream>>>(s_mask, w1, W2, W3, w4, pos, neg,
                                           u, partials, 1, UPDBLK);
    upd_kernel<<<UPDBLK, 256, 0, stream>>>(s_mask, w1, W2, W3, w4, pos, neg,
                                           u, partials, 2, UPDBLK);
    final_kernel<<<1, 128, 0, stream>>>(partials + (size_t)3 * SLOT, u, vptr,
                                        W6, W7, w5, out);
}

// Round 7
// 338.306 us; speedup vs baseline: 3.1912x; 1.1291x over previous
//
#include <hip/hip_runtime.h>

#define NN 16384
#define DIM 64
#define SEGS 4                   // 16KB segments per 64KB row
#define NTILES (NN * SEGS)       // 65536 wave-tiles
#define TBLK (NTILES / 4)        // 16384 blocks, 4 waves each, flat dispatch order
#define CBLK 2048                // combine/init blocks
#define ROWS_PER_BLK 8           // NN / CBLK
#define UPDBLK 256               // update blocks: 1 per CU
#define RPB_U (NN / UPDBLK)      // 64 rows per update block
#define SLOT (CBLK * DIM)        // floats per partials slot

typedef float floatx4 __attribute__((ext_vector_type(4)));

// ---- flat-order tiled read: tile = (row, seg), one wave per tile.
// Tiles processed in flat address order => sliding contiguous window across
// the whole grid (memcpy-like), instead of 2048 scattered row streams. ----
__global__ __launch_bounds__(256, 8) void tile_rowsum_kernel(
    const float* __restrict__ g,
    float* __restrict__ psegs, float* __restrict__ nsegs)
{
    const int tid  = threadIdx.x;
    const int w    = tid >> 6;
    const int lane = tid & 63;
    const int tile = blockIdx.x * 4 + w;
    const int row  = tile >> 2;
    const int seg  = tile & 3;
    const floatx4* base =
        reinterpret_cast<const floatx4*>(g + (size_t)row * NN + seg * (NN / SEGS));

    float s = 0.f, a = 0.f;   // s = sum(x), a = sum(|x|)
    #pragma unroll
    for (int b8 = 0; b8 < 2; ++b8) {      // 16 float4/lane = 2 batches of 8
        floatx4 v[8];
        #pragma unroll
        for (int j = 0; j < 8; ++j)
            v[j] = __builtin_nontemporal_load(&base[(b8 * 8 + j) * 64 + lane]);
        #pragma unroll
        for (int j = 0; j < 8; ++j) {
            s += v[j].x + v[j].y + v[j].z + v[j].w;
            a += fabsf(v[j].x) + fabsf(v[j].y) + fabsf(v[j].z) + fabsf(v[j].w);
        }
    }
    #pragma unroll
    for (int o = 1; o < 64; o <<= 1) {
        s += __shfl_xor(s, o, 64);
        a += __shfl_xor(a, o, 64);
    }
    if (lane == 0) {
        psegs[tile] = 0.5f * (a + s);   // sum(relu(x)) over segment
        nsegs[tile] = 0.5f * (a - s);   // sum(relu(-x)) over segment
    }
}

// ---- combine segs -> pos/neg, u1 = relu(base), partials slot 0 ----
__global__ __launch_bounds__(256) void init_kernel(
    const float* __restrict__ psegs, const float* __restrict__ nsegs,
    const int* __restrict__ s_mask,
    const float* __restrict__ W3, const float* __restrict__ w4,
    const float* __restrict__ w1,
    float* __restrict__ pos, float* __restrict__ neg,
    float* __restrict__ u, float* __restrict__ partials)
{
    __shared__ float a3s[DIM], b3s[DIM], w1s[DIM];
    __shared__ float ps[4][DIM];
    const int tid  = threadIdx.x;
    const int wid  = tid >> 6;
    const int lane = tid & 63;
    const int row0 = blockIdx.x * ROWS_PER_BLK;

    if (tid < DIM) {  // a3 = W3@relu(w4), b3 = W3@relu(-w4)
        float a = 0.f, bb = 0.f;
        for (int k = 0; k < DIM; ++k) {
            const float w = W3[tid * DIM + k];
            a  += w * fmaxf(w4[k], 0.f);
            bb += w * fmaxf(-w4[k], 0.f);
        }
        a3s[tid] = a; b3s[tid] = bb; w1s[tid] = w1[tid];
    }
    __syncthreads();

    float uacc = 0.f;
    #pragma unroll
    for (int rr = 0; rr < 2; ++rr) {
        const int row = row0 + wid * 2 + rr;
        const float p = psegs[row * 4] + psegs[row * 4 + 1]
                      + psegs[row * 4 + 2] + psegs[row * 4 + 3];
        const float n = nsegs[row * 4] + nsegs[row * 4 + 1]
                      + nsegs[row * 4 + 2] + nsegs[row * 4 + 3];
        const float x  = (float)s_mask[row];
        const float uu = fmaxf(x * w1s[lane] + p * a3s[lane] + n * b3s[lane], 0.f);
        u[(size_t)row * DIM + lane] = uu;
        uacc += uu;
        if (lane == 0) { pos[row] = p; neg[row] = n; }
    }
    ps[wid][lane] = uacc;
    __syncthreads();
    if (tid < DIM)
        partials[blockIdx.x * DIM + tid] = ps[0][tid] + ps[1][tid] + ps[2][tid] + ps[3][tid];
}

// ---- one message-passing iteration ----
__global__ __launch_bounds__(256) void upd_kernel(
    const int* __restrict__ s_mask, const float* __restrict__ w1,
    const float* __restrict__ W2, const float* __restrict__ W3,
    const float* __restrict__ w4,
    const float* __restrict__ pos, const float* __restrict__ neg,
    float* __restrict__ u, float* __restrict__ partials,
    int slot_in, int Pcount)
{
    __shared__ float a3s[DIM], b3s[DIM], w1s[DIM], ss[DIM];
    __shared__ float posr[RPB_U], negr[RPB_U], xr[RPB_U];
    __shared__ float4 ps4[16][16];
    __shared__ float ps[4][DIM];
    const int tid  = threadIdx.x;
    const int row0 = blockIdx.x * RPB_U;

    if (tid < 64) {
        float a = 0.f, bb = 0.f;
        for (int k = 0; k < DIM; ++k) {
            const float w = W3[tid * DIM + k];
            a  += w * fmaxf(w4[k], 0.f);
            bb += w * fmaxf(-w4[k], 0.f);
        }
        a3s[tid] = a; b3s[tid] = bb; w1s[tid] = w1[tid];
    } else if (tid < 128) {
        posr[tid - 64] = pos[row0 + tid - 64];
    } else if (tid < 192) {
        negr[tid - 128] = neg[row0 + tid - 128];
    } else {
        xr[tid - 192] = (float)s_mask[row0 + tid - 192];
    }

    {
        const int d4 = tid & 15, s16 = tid >> 4;
        const float4* pin = reinterpret_cast<const float4*>(partials + (size_t)slot_in * SLOT);
        float4 a4 = {0.f, 0.f, 0.f, 0.f};
        for (int p = s16; p < Pcount; p += 16) {
            const float4 t4 = pin[p * 16 + d4];
            a4.x += t4.x; a4.y += t4.y; a4.z += t4.z; a4.w += t4.w;
        }
        ps4[s16][d4] = a4;
        __syncthreads();
        if (tid < 16) {
            float4 r = ps4[0][tid];
            #pragma unroll
            for (int s = 1; s < 16; ++s) {
                const float4 t4 = ps4[s][tid];
                r.x += t4.x; r.y += t4.y; r.z += t4.z; r.w += t4.w;
            }
            reinterpret_cast<float4*>(ss)[tid] = r;
        }
        __syncthreads();
    }

    const int d = tid & 63, sub = tid >> 6;
    float w2r[DIM];
    #pragma unroll
    for (int k = 0; k < DIM; k += 4) {
        const float4 t = *reinterpret_cast<const float4*>(&W2[d * DIM + k]);
        w2r[k] = t.x; w2r[k + 1] = t.y; w2r[k + 2] = t.z; w2r[k + 3] = t.w;
    }
    float c2 = 0.f;
    #pragma unroll
    for (int k = 0; k < DIM; ++k) c2 += w2r[k] * ss[k];

    float uacc = 0.f;
    for (int r = sub; r < RPB_U; r += 4) {
        const int row = row0 + r;
        const float4* ur = reinterpret_cast<const float4*>(u + (size_t)row * DIM);
        float aA = 0.f, aB = 0.f, aC = 0.f, aD = 0.f;
        #pragma unroll
        for (int k4 = 0; k4 < 16; k4 += 4) {
            const float4 x0 = ur[k4 + 0];
            aA += w2r[(k4+0)*4+0]*x0.x + w2r[(k4+0)*4+1]*x0.y + w2r[(k4+0)*4+2]*x0.z + w2r[(k4+0)*4+3]*x0.w;
            const float4 x1 = ur[k4 + 1];
            aB += w2r[(k4+1)*4+0]*x1.x + w2r[(k4+1)*4+1]*x1.y + w2r[(k4+1)*4+2]*x1.z + w2r[(k4+1)*4+3]*x1.w;
            const float4 x2 = ur[k4 + 2];
            aC += w2r[(k4+2)*4+0]*x2.x + w2r[(k4+2)*4+1]*x2.y + w2r[(k4+2)*4+2]*x2.z + w2r[(k4+2)*4+3]*x2.w;
            const float4 x3 = ur[k4 + 3];
            aD += w2r[(k4+3)*4+0]*x3.x + w2r[(k4+3)*4+1]*x3.y + w2r[(k4+3)*4+2]*x3.z + w2r[(k4+3)*4+3]*x3.w;
        }
        const float acc = (aA + aB) + (aC + aD);
        const float uu = fmaxf(xr[r] * w1s[d] + posr[r] * a3s[d] + negr[r] * b3s[d] + c2 - acc, 0.f);
        u[(size_t)row * DIM + d] = uu;
        uacc += uu;
    }
    ps[sub][d] = uacc;
    __syncthreads();
    if (tid < DIM)
        partials[(size_t)(slot_in + 1) * SLOT + blockIdx.x * DIM + tid] =
            ps[0][tid] + ps[1][tid] + ps[2][tid] + ps[3][tid];
}

// ---- q(v) head ----
__global__ void final_kernel(const float* __restrict__ partials_slot,
                             const float* __restrict__ u, const int* __restrict__ vptr,
                             const float* __restrict__ W6, const float* __restrict__ W7,
                             const float* __restrict__ w5, float* __restrict__ out)
{
    __shared__ float ps[2][DIM], ss[DIM], hred[128];
    const int tid = threadIdx.x;
    const int d = tid & 63, sub = tid >> 6;
    float acc = 0.f;
    for (int p = sub; p < UPDBLK; p += 2) acc += partials_slot[p * DIM + d];
    ps[sub][d] = acc;
    __syncthreads();
    if (tid < 64) ss[tid] = ps[0][tid] + ps[1][tid];
    __syncthreads();
    const int v = *vptr;
    float h = 0.f;
    if (tid < 64) {
        #pragma unroll
        for (int k = 0; k < DIM; ++k) h += W6[tid * DIM + k] * ss[k];
    } else {
        const float* uv = u + (size_t)v * DIM;
        #pragma unroll
        for (int k = 0; k < DIM; ++k) h += W7[(tid - 64) * DIM + k] * uv[k];
    }
    hred[tid] = fmaxf(h, 0.f) * w5[tid];
    __syncthreads();
    if (tid == 0) {
        float s = 0.f;
        for (int i = 0; i < 128; ++i) s += hred[i];
        out[0] = s;
    }
}

extern "C" void kernel_launch(void* const* d_in, const int* in_sizes, int n_in,
                              void* d_out, int out_size, void* d_ws, size_t ws_size,
                              hipStream_t stream) {
    const float* graph  = (const float*)d_in[0];
    const int*   s_mask = (const int*)d_in[1];
    const int*   vptr   = (const int*)d_in[2];
    const float* w1     = (const float*)d_in[3];
    const float* W2     = (const float*)d_in[4];
    const float* W3     = (const float*)d_in[5];
    const float* w4     = (const float*)d_in[6];
    const float* w5     = (const float*)d_in[7];
    const float* W6     = (const float*)d_in[8];
    const float* W7     = (const float*)d_in[9];
    float* out = (float*)d_out;

    float* ws       = (float*)d_ws;
    float* pos      = ws;                          // NN
    float* neg      = pos + NN;                    // NN
    float* u        = neg + NN;                    // NN*DIM
    float* partials = u + (size_t)NN * DIM;        // 4 * SLOT
    float* psegs    = partials + (size_t)4 * SLOT; // NTILES
    float* nsegs    = psegs + NTILES;              // NTILES

    tile_rowsum_kernel<<<TBLK, 256, 0, stream>>>(graph, psegs, nsegs);
    init_kernel<<<CBLK, 256, 0, stream>>>(psegs, nsegs, s_mask, W3, w4, w1,
                                          pos, neg, u, partials);
    upd_kernel<<<UPDBLK, 256, 0, stream>>>(s_mask, w1, W2, W3, w4, pos, neg,
                                           u, partials, 0, CBLK);
    upd_kernel<<<UPDBLK, 256, 0, stream>>>(s_mask, w1, W2, W3, w4, pos, neg,
                                           u, partials, 1, UPDBLK);
    upd_kernel<<<UPDBLK, 256, 0, stream>>>(s_mask, w1, W2, W3, w4, pos, neg,
                                           u, partials, 2, UPDBLK);
    final_kernel<<<1, 128, 0, stream>>>(partials + (size_t)3 * SLOT, u, vptr,
                                        W6, W7, w5, out);
}

// Round 8
// 305.471 us; speedup vs baseline: 3.5342x; 1.1075x over previous
//
#include <hip/hip_runtime.h>

#define NN 16384
#define DIM 64
#define SEGS 4                   // 16KB segments per 64KB row
#define NTILES (NN * SEGS)       // 65536 tiles = 65536 blocks (16KB each)
#define CBLK 2048                // combine/init blocks
#define ROWS_PER_BLK 8           // NN / CBLK
#define UPDBLK 256               // update blocks: 1 per CU
#define RPB_U (NN / UPDBLK)      // 64 rows per update block
#define SLOT (CBLK * DIM)        // floats per partials slot

typedef float floatx4 __attribute__((ext_vector_type(4)));

// ---- flat-order tiled read: one BLOCK per 16KB tile (4 waves x 4KB).
// Resident window = 2048 blocks x 16KB = 32MB contiguous sliding window. ----
__global__ __launch_bounds__(256, 8) void tile_rowsum_kernel(
    const float* __restrict__ g, float2* __restrict__ pn)
{
    const int tid  = threadIdx.x;
    const int w    = tid >> 6;
    const int lane = tid & 63;
    const floatx4* base =
        reinterpret_cast<const floatx4*>(g + (size_t)blockIdx.x * 4096 + w * 1024);

    floatx4 v[4];
    #pragma unroll
    for (int j = 0; j < 4; ++j)
        v[j] = __builtin_nontemporal_load(&base[j * 64 + lane]);
    float s = 0.f, a = 0.f;   // s = sum(x), a = sum(|x|)
    #pragma unroll
    for (int j = 0; j < 4; ++j) {
        s += v[j].x + v[j].y + v[j].z + v[j].w;
        a += fabsf(v[j].x) + fabsf(v[j].y) + fabsf(v[j].z) + fabsf(v[j].w);
    }
    #pragma unroll
    for (int o = 1; o < 64; o <<= 1) {
        s += __shfl_xor(s, o, 64);
        a += __shfl_xor(a, o, 64);
    }
    __shared__ float sp[4], sa[4];
    if (lane == 0) { sp[w] = s; sa[w] = a; }
    __syncthreads();
    if (tid == 0) {
        const float S = sp[0] + sp[1] + sp[2] + sp[3];
        const float A = sa[0] + sa[1] + sa[2] + sa[3];
        pn[blockIdx.x] = make_float2(0.5f * (A + S), 0.5f * (A - S));
    }
}

// ---- combine segs -> pos/neg, u1 = relu(base), partials slot 0 ----
__global__ __launch_bounds__(256) void init_kernel(
    const float2* __restrict__ pn, const int* __restrict__ s_mask,
    const float* __restrict__ W3, const float* __restrict__ w4,
    const float* __restrict__ w1,
    float* __restrict__ pos, float* __restrict__ neg,
    float* __restrict__ u, float* __restrict__ partials)
{
    __shared__ float a3s[DIM], b3s[DIM], w1s[DIM];
    __shared__ float ps[4][DIM];
    const int tid  = threadIdx.x;
    const int wid  = tid >> 6;
    const int lane = tid & 63;
    const int row0 = blockIdx.x * ROWS_PER_BLK;

    if (tid < DIM) {  // a3 = W3@relu(w4), b3 = W3@relu(-w4)
        float a = 0.f, bb = 0.f;
        for (int k = 0; k < DIM; ++k) {
            const float w = W3[tid * DIM + k];
            a  += w * fmaxf(w4[k], 0.f);
            bb += w * fmaxf(-w4[k], 0.f);
        }
        a3s[tid] = a; b3s[tid] = bb; w1s[tid] = w1[tid];
    }
    __syncthreads();

    float uacc = 0.f;
    #pragma unroll
    for (int rr = 0; rr < 2; ++rr) {
        const int row = row0 + wid * 2 + rr;
        const float2 t0 = pn[row * 4],     t1 = pn[row * 4 + 1];
        const float2 t2 = pn[row * 4 + 2], t3 = pn[row * 4 + 3];
        const float p = t0.x + t1.x + t2.x + t3.x;
        const float n = t0.y + t1.y + t2.y + t3.y;
        const float x  = (float)s_mask[row];
        const float uu = fmaxf(x * w1s[lane] + p * a3s[lane] + n * b3s[lane], 0.f);
        u[(size_t)row * DIM + lane] = uu;
        uacc += uu;
        if (lane == 0) { pos[row] = p; neg[row] = n; }
    }
    ps[wid][lane] = uacc;
    __syncthreads();
    if (tid < DIM)
        partials[blockIdx.x * DIM + tid] = ps[0][tid] + ps[1][tid] + ps[2][tid] + ps[3][tid];
}

// ---- one message-passing iteration ----
__global__ __launch_bounds__(256) void upd_kernel(
    const int* __restrict__ s_mask, const float* __restrict__ w1,
    const float* __restrict__ W2, const float* __restrict__ W3,
    const float* __restrict__ w4,
    const float* __restrict__ pos, const float* __restrict__ neg,
    float* __restrict__ u, float* __restrict__ partials,
    int slot_in, int Pcount)
{
    __shared__ float a3s[DIM], b3s[DIM], w1s[DIM], ss[DIM];
    __shared__ float posr[RPB_U], negr[RPB_U], xr[RPB_U];
    __shared__ float4 ps4[16][16];
    __shared__ float ps[4][DIM];
    const int tid  = threadIdx.x;
    const int row0 = blockIdx.x * RPB_U;

    if (tid < 64) {
        float a = 0.f, bb = 0.f;
        for (int k = 0; k < DIM; ++k) {
            const float w = W3[tid * DIM + k];
            a  += w * fmaxf(w4[k], 0.f);
            bb += w * fmaxf(-w4[k], 0.f);
        }
        a3s[tid] = a; b3s[tid] = bb; w1s[tid] = w1[tid];
    } else if (tid < 128) {
        posr[tid - 64] = pos[row0 + tid - 64];
    } else if (tid < 192) {
        negr[tid - 128] = neg[row0 + tid - 128];
    } else {
        xr[tid - 192] = (float)s_mask[row0 + tid - 192];
    }

    {
        const int d4 = tid & 15, s16 = tid >> 4;
        const float4* pin = reinterpret_cast<const float4*>(partials + (size_t)slot_in * SLOT);
        float4 a4 = {0.f, 0.f, 0.f, 0.f};
        for (int p = s16; p < Pcount; p += 16) {
            const float4 t4 = pin[p * 16 + d4];
            a4.x += t4.x; a4.y += t4.y; a4.z += t4.z; a4.w += t4.w;
        }
        ps4[s16][d4] = a4;
        __syncthreads();
        if (tid < 16) {
            float4 r = ps4[0][tid];
            #pragma unroll
            for (int s = 1; s < 16; ++s) {
                const float4 t4 = ps4[s][tid];
                r.x += t4.x; r.y += t4.y; r.z += t4.z; r.w += t4.w;
            }
            reinterpret_cast<float4*>(ss)[tid] = r;
        }
        __syncthreads();
    }

    const int d = tid & 63, sub = tid >> 6;
    float w2r[DIM];
    #pragma unroll
    for (int k = 0; k < DIM; k += 4) {
        const float4 t = *reinterpret_cast<const float4*>(&W2[d * DIM + k]);
        w2r[k] = t.x; w2r[k + 1] = t.y; w2r[k + 2] = t.z; w2r[k + 3] = t.w;
    }
    float c2 = 0.f;
    #pragma unroll
    for (int k = 0; k < DIM; ++k) c2 += w2r[k] * ss[k];

    float uacc = 0.f;
    for (int r = sub; r < RPB_U; r += 4) {
        const int row = row0 + r;
        const float4* ur = reinterpret_cast<const float4*>(u + (size_t)row * DIM);
        float aA = 0.f, aB = 0.f, aC = 0.f, aD = 0.f;
        #pragma unroll
        for (int k4 = 0; k4 < 16; k4 += 4) {
            const float4 x0 = ur[k4 + 0];
            aA += w2r[(k4+0)*4+0]*x0.x + w2r[(k4+0)*4+1]*x0.y + w2r[(k4+0)*4+2]*x0.z + w2r[(k4+0)*4+3]*x0.w;
            const float4 x1 = ur[k4 + 1];
            aB += w2r[(k4+1)*4+0]*x1.x + w2r[(k4+1)*4+1]*x1.y + w2r[(k4+1)*4+2]*x1.z + w2r[(k4+1)*4+3]*x1.w;
            const float4 x2 = ur[k4 + 2];
            aC += w2r[(k4+2)*4+0]*x2.x + w2r[(k4+2)*4+1]*x2.y + w2r[(k4+2)*4+2]*x2.z + w2r[(k4+2)*4+3]*x2.w;
            const float4 x3 = ur[k4 + 3];
            aD += w2r[(k4+3)*4+0]*x3.x + w2r[(k4+3)*4+1]*x3.y + w2r[(k4+3)*4+2]*x3.z + w2r[(k4+3)*4+3]*x3.w;
        }
        const float acc = (aA + aB) + (aC + aD);
        const float uu = fmaxf(xr[r] * w1s[d] + posr[r] * a3s[d] + negr[r] * b3s[d] + c2 - acc, 0.f);
        u[(size_t)row * DIM + d] = uu;
        uacc += uu;
    }
    ps[sub][d] = uacc;
    __syncthreads();
    if (tid < DIM)
        partials[(size_t)(slot_in + 1) * SLOT + blockIdx.x * DIM + tid] =
            ps[0][tid] + ps[1][tid] + ps[2][tid] + ps[3][tid];
}

// ---- q(v) head ----
__global__ void final_kernel(const float* __restrict__ partials_slot,
                             const float* __restrict__ u, const int* __restrict__ vptr,
                             const float* __restrict__ W6, const float* __restrict__ W7,
                             const float* __restrict__ w5, float* __restrict__ out)
{
    __shared__ float ps[2][DIM], ss[DIM], hred[128];
    const int tid = threadIdx.x;
    const int d = tid & 63, sub = tid >> 6;
    float acc = 0.f;
    for (int p = sub; p < UPDBLK; p += 2) acc += partials_slot[p * DIM + d];
    ps[sub][d] = acc;
    __syncthreads();
    if (tid < 64) ss[tid] = ps[0][tid] + ps[1][tid];
    __syncthreads();
    const int v = *vptr;
    float h = 0.f;
    if (tid < 64) {
        #pragma unroll
        for (int k = 0; k < DIM; ++k) h += W6[tid * DIM + k] * ss[k];
    } else {
        const float* uv = u + (size_t)v * DIM;
        #pragma unroll
        for (int k = 0; k < DIM; ++k) h += W7[(tid - 64) * DIM + k] * uv[k];
    }
    hred[tid] = fmaxf(h, 0.f) * w5[tid];
    __syncthreads();
    if (tid == 0) {
        float s = 0.f;
        for (int i = 0; i < 128; ++i) s += hred[i];
        out[0] = s;
    }
}

extern "C" void kernel_launch(void* const* d_in, const int* in_sizes, int n_in,
                              void* d_out, int out_size, void* d_ws, size_t ws_size,
                              hipStream_t stream) {
    const float* graph  = (const float*)d_in[0];
    const int*   s_mask = (const int*)d_in[1];
    const int*   vptr   = (const int*)d_in[2];
    const float* w1     = (const float*)d_in[3];
    const float* W2     = (const float*)d_in[4];
    const float* W3     = (const float*)d_in[5];
    const float* w4     = (const float*)d_in[6];
    const float* w5     = (const float*)d_in[7];
    const float* W6     = (const float*)d_in[8];
    const float* W7     = (const float*)d_in[9];
    float* out = (float*)d_out;

    float* ws       = (float*)d_ws;
    float* pos      = ws;                          // NN
    float* neg      = pos + NN;                    // NN
    float* u        = neg + NN;                    // NN*DIM
    float* partials = u + (size_t)NN * DIM;        // 4 * SLOT
    float2* pn      = (float2*)(partials + (size_t)4 * SLOT);  // NTILES float2

    tile_rowsum_kernel<<<NTILES, 256, 0, stream>>>(graph, pn);
    init_kernel<<<CBLK, 256, 0, stream>>>(pn, s_mask, W3, w4, w1,
                                          pos, neg, u, partials);
    upd_kernel<<<UPDBLK, 256, 0, stream>>>(s_mask, w1, W2, W3, w4, pos, neg,
                                           u, partials, 0, CBLK);
    upd_kernel<<<UPDBLK, 256, 0, stream>>>(s_mask, w1, W2, W3, w4, pos, neg,
                                           u, partials, 1, UPDBLK);
    upd_kernel<<<UPDBLK, 256, 0, stream>>>(s_mask, w1, W2, W3, w4, pos, neg,
                                           u, partials, 2, UPDBLK);
    final_kernel<<<1, 128, 0, stream>>>(partials + (size_t)3 * SLOT, u, vptr,
                                        W6, W7, w5, out);
}

// Round 9
// 301.673 us; speedup vs baseline: 3.5787x; 1.0126x over previous
//
#include <hip/hip_runtime.h>

#define NN 16384
#define DIM 64
#define SEGS 4                   // 16KB segments per 64KB row
#define NTILES (NN * SEGS)       // 65536 tiles = 65536 blocks (16KB each)
#define CBLK 2048                // combine/init blocks
#define ROWS_PER_BLK 8           // NN / CBLK
#define UPDBLK 256               // update blocks: 1 per CU
#define RPB_U (NN / UPDBLK)      // 64 rows per update block
#define SLOT (CBLK * DIM)        // floats per partials slot

typedef float floatx4 __attribute__((ext_vector_type(4)));

// ---- flat-order tiled read with XCD-contiguous swizzle.
// Blocks round-robin across 8 XCDs; swizzle gives XCD x the contiguous tile
// range [x*8192, (x+1)*8192) so each XCD streams one private 134MB region
// sequentially (resident window ~4MB contiguous per XCD). ----
__global__ __launch_bounds__(256, 8) void tile_rowsum_kernel(
    const float* __restrict__ g, float2* __restrict__ pn)
{
    const int tid  = threadIdx.x;
    const int w    = tid >> 6;
    const int lane = tid & 63;
    const int tile = (blockIdx.x & 7) * (NTILES / 8) + (blockIdx.x >> 3);
    const floatx4* base =
        reinterpret_cast<const floatx4*>(g + (size_t)tile * 4096 + w * 1024);

    floatx4 v[4];
    #pragma unroll
    for (int j = 0; j < 4; ++j)
        v[j] = __builtin_nontemporal_load(&base[j * 64 + lane]);
    float s = 0.f, a = 0.f;   // s = sum(x), a = sum(|x|)
    #pragma unroll
    for (int j = 0; j < 4; ++j) {
        s += v[j].x + v[j].y + v[j].z + v[j].w;
        a += fabsf(v[j].x) + fabsf(v[j].y) + fabsf(v[j].z) + fabsf(v[j].w);
    }
    #pragma unroll
    for (int o = 1; o < 64; o <<= 1) {
        s += __shfl_xor(s, o, 64);
        a += __shfl_xor(a, o, 64);
    }
    __shared__ float sp[4], sa[4];
    if (lane == 0) { sp[w] = s; sa[w] = a; }
    __syncthreads();
    if (tid == 0) {
        const float S = sp[0] + sp[1] + sp[2] + sp[3];
        const float A = sa[0] + sa[1] + sa[2] + sa[3];
        pn[tile] = make_float2(0.5f * (A + S), 0.5f * (A - S));
    }
}

// ---- combine segs -> pos/neg, u1 = relu(base), partials slot 0 ----
__global__ __launch_bounds__(256) void init_kernel(
    const float2* __restrict__ pn, const int* __restrict__ s_mask,
    const float* __restrict__ W3, const float* __restrict__ w4,
    const float* __restrict__ w1,
    float* __restrict__ pos, float* __restrict__ neg,
    float* __restrict__ u, float* __restrict__ partials)
{
    __shared__ float a3s[DIM], b3s[DIM], w1s[DIM];
    __shared__ float ps[4][DIM];
    const int tid  = threadIdx.x;
    const int wid  = tid >> 6;
    const int lane = tid & 63;
    const int row0 = blockIdx.x * ROWS_PER_BLK;

    if (tid < DIM) {  // a3 = W3@relu(w4), b3 = W3@relu(-w4)
        float a = 0.f, bb = 0.f;
        for (int k = 0; k < DIM; ++k) {
            const float w = W3[tid * DIM + k];
            a  += w * fmaxf(w4[k], 0.f);
            bb += w * fmaxf(-w4[k], 0.f);
        }
        a3s[tid] = a; b3s[tid] = bb; w1s[tid] = w1[tid];
    }
    __syncthreads();

    float uacc = 0.f;
    #pragma unroll
    for (int rr = 0; rr < 2; ++rr) {
        const int row = row0 + wid * 2 + rr;
        const float2 t0 = pn[row * 4],     t1 = pn[row * 4 + 1];
        const float2 t2 = pn[row * 4 + 2], t3 = pn[row * 4 + 3];
        const float p = t0.x + t1.x + t2.x + t3.x;
        const float n = t0.y + t1.y + t2.y + t3.y;
        const float x  = (float)s_mask[row];
        const float uu = fmaxf(x * w1s[lane] + p * a3s[lane] + n * b3s[lane], 0.f);
        u[(size_t)row * DIM + lane] = uu;
        uacc += uu;
        if (lane == 0) { pos[row] = p; neg[row] = n; }
    }
    ps[wid][lane] = uacc;
    __syncthreads();
    if (tid < DIM)
        partials[blockIdx.x * DIM + tid] = ps[0][tid] + ps[1][tid] + ps[2][tid] + ps[3][tid];
}

// ---- one message-passing iteration ----
__global__ __launch_bounds__(256) void upd_kernel(
    const int* __restrict__ s_mask, const float* __restrict__ w1,
    const float* __restrict__ W2, const float* __restrict__ W3,
    const float* __restrict__ w4,
    const float* __restrict__ pos, const float* __restrict__ neg,
    float* __restrict__ u, float* __restrict__ partials,
    int slot_in, int Pcount)
{
    __shared__ float a3s[DIM], b3s[DIM], w1s[DIM], ss[DIM];
    __shared__ float posr[RPB_U], negr[RPB_U], xr[RPB_U];
    __shared__ float4 ps4[16][16];
    __shared__ float ps[4][DIM];
    const int tid  = threadIdx.x;
    const int row0 = blockIdx.x * RPB_U;

    if (tid < 64) {
        float a = 0.f, bb = 0.f;
        for (int k = 0; k < DIM; ++k) {
            const float w = W3[tid * DIM + k];
            a  += w * fmaxf(w4[k], 0.f);
            bb += w * fmaxf(-w4[k], 0.f);
        }
        a3s[tid] = a; b3s[tid] = bb; w1s[tid] = w1[tid];
    } else if (tid < 128) {
        posr[tid - 64] = pos[row0 + tid - 64];
    } else if (tid < 192) {
        negr[tid - 128] = neg[row0 + tid - 128];
    } else {
        xr[tid - 192] = (float)s_mask[row0 + tid - 192];
    }

    {
        const int d4 = tid & 15, s16 = tid >> 4;
        const float4* pin = reinterpret_cast<const float4*>(partials + (size_t)slot_in * SLOT);
        float4 a4 = {0.f, 0.f, 0.f, 0.f};
        for (int p = s16; p < Pcount; p += 16) {
            const float4 t4 = pin[p * 16 + d4];
            a4.x += t4.x; a4.y += t4.y; a4.z += t4.z; a4.w += t4.w;
        }
        ps4[s16][d4] = a4;
        __syncthreads();
        if (tid < 16) {
            float4 r = ps4[0][tid];
            #pragma unroll
            for (int s = 1; s < 16; ++s) {
                const float4 t4 = ps4[s][tid];
                r.x += t4.x; r.y += t4.y; r.z += t4.z; r.w += t4.w;
            }
            reinterpret_cast<float4*>(ss)[tid] = r;
        }
        __syncthreads();
    }

    const int d = tid & 63, sub = tid >> 6;
    float w2r[DIM];
    #pragma unroll
    for (int k = 0; k < DIM; k += 4) {
        const float4 t = *reinterpret_cast<const float4*>(&W2[d * DIM + k]);
        w2r[k] = t.x; w2r[k + 1] = t.y; w2r[k + 2] = t.z; w2r[k + 3] = t.w;
    }
    float c2 = 0.f;
    #pragma unroll
    for (int k = 0; k < DIM; ++k) c2 += w2r[k] * ss[k];

    float uacc = 0.f;
    for (int r = sub; r < RPB_U; r += 4) {
        const int row = row0 + r;
        const float4* ur = reinterpret_cast<const float4*>(u + (size_t)row * DIM);
        float aA = 0.f, aB = 0.f, aC = 0.f, aD = 0.f;
        #pragma unroll
        for (int k4 = 0; k4 < 16; k4 += 4) {
            const float4 x0 = ur[k4 + 0];
            aA += w2r[(k4+0)*4+0]*x0.x + w2r[(k4+0)*4+1]*x0.y + w2r[(k4+0)*4+2]*x0.z + w2r[(k4+0)*4+3]*x0.w;
            const float4 x1 = ur[k4 + 1];
            aB += w2r[(k4+1)*4+0]*x1.x + w2r[(k4+1)*4+1]*x1.y + w2r[(k4+1)*4+2]*x1.z + w2r[(k4+1)*4+3]*x1.w;
            const float4 x2 = ur[k4 + 2];
            aC += w2r[(k4+2)*4+0]*x2.x + w2r[(k4+2)*4+1]*x2.y + w2r[(k4+2)*4+2]*x2.z + w2r[(k4+2)*4+3]*x2.w;
            const float4 x3 = ur[k4 + 3];
            aD += w2r[(k4+3)*4+0]*x3.x + w2r[(k4+3)*4+1]*x3.y + w2r[(k4+3)*4+2]*x3.z + w2r[(k4+3)*4+3]*x3.w;
        }
        const float acc = (aA + aB) + (aC + aD);
        const float uu = fmaxf(xr[r] * w1s[d] + posr[r] * a3s[d] + negr[r] * b3s[d] + c2 - acc, 0.f);
        u[(size_t)row * DIM + d] = uu;
        uacc += uu;
    }
    ps[sub][d] = uacc;
    __syncthreads();
    if (tid < DIM)
        partials[(size_t)(slot_in + 1) * SLOT + blockIdx.x * DIM + tid] =
            ps[0][tid] + ps[1][tid] + ps[2][tid] + ps[3][tid];
}

// ---- q(v) head ----
__global__ void final_kernel(const float* __restrict__ partials_slot,
                             const float* __restrict__ u, const int* __restrict__ vptr,
                             const float* __restrict__ W6, const float* __restrict__ W7,
                             const float* __restrict__ w5, float* __restrict__ out)
{
    __shared__ float ps[2][DIM], ss[DIM], hred[128];
    const int tid = threadIdx.x;
    const int d = tid & 63, sub = tid >> 6;
    float acc = 0.f;
    for (int p = sub; p < UPDBLK; p += 2) acc += partials_slot[p * DIM + d];
    ps[sub][d] = acc;
    __syncthreads();
    if (tid < 64) ss[tid] = ps[0][tid] + ps[1][tid];
    __syncthreads();
    const int v = *vptr;
    float h = 0.f;
    if (tid < 64) {
        #pragma unroll
        for (int k = 0; k < DIM; ++k) h += W6[tid * DIM + k] * ss[k];
    } else {
        const float* uv = u + (size_t)v * DIM;
        #pragma unroll
        for (int k = 0; k < DIM; ++k) h += W7[(tid - 64) * DIM + k] * uv[k];
    }
    hred[tid] = fmaxf(h, 0.f) * w5[tid];
    __syncthreads();
    if (tid == 0) {
        float s = 0.f;
        for (int i = 0; i < 128; ++i) s += hred[i];
        out[0] = s;
    }
}

extern "C" void kernel_launch(void* const* d_in, const int* in_sizes, int n_in,
                              void* d_out, int out_size, void* d_ws, size_t ws_size,
                              hipStream_t stream) {
    const float* graph  = (const float*)d_in[0];
    const int*   s_mask = (const int*)d_in[1];
    const int*   vptr   = (const int*)d_in[2];
    const float* w1     = (const float*)d_in[3];
    const float* W2     = (const float*)d_in[4];
    const float* W3     = (const float*)d_in[5];
    const float* w4     = (const float*)d_in[6];
    const float* w5     = (const float*)d_in[7];
    const float* W6     = (const float*)d_in[8];
    const float* W7     = (const float*)d_in[9];
    float* out = (float*)d_out;

    float* ws       = (float*)d_ws;
    float* pos      = ws;                          // NN
    float* neg      = pos + NN;                    // NN
    float* u        = neg + NN;                    // NN*DIM
    float* partials = u + (size_t)NN * DIM;        // 4 * SLOT
    float2* pn      = (float2*)(partials + (size_t)4 * SLOT);  // NTILES float2

    tile_rowsum_kernel<<<NTILES, 256, 0, stream>>>(graph, pn);
    init_kernel<<<CBLK, 256, 0, stream>>>(pn, s_mask, W3, w4, w1,
                                          pos, neg, u, partials);
    upd_kernel<<<UPDBLK, 256, 0, stream>>>(s_mask, w1, W2, W3, w4, pos, neg,
                                           u, partials, 0, CBLK);
    upd_kernel<<<UPDBLK, 256, 0, stream>>>(s_mask, w1, W2, W3, w4, pos, neg,
                                           u, partials, 1, UPDBLK);
    upd_kernel<<<UPDBLK, 256, 0, stream>>>(s_mask, w1, W2, W3, w4, pos, neg,
                                           u, partials, 2, UPDBLK);
    final_kernel<<<1, 128, 0, stream>>>(partials + (size_t)3 * SLOT, u, vptr,
                                        W6, W7, w5, out);
}